// Round 10
// baseline (1262.403 us; speedup 1.0000x reference)
//
#include <hip/hip_runtime.h>
#include <hip/hip_bf16.h>
#include <stdint.h>

#define B_ 8
#define T_ 10
#define N_ 50
#define IN_ 6
#define H_ 256
#define K_ 4
#define E_ 2450
#define ROWS 400           // B_*N_
#define AP 102400          // ROWS*H_

typedef __attribute__((ext_vector_type(8))) __bf16 bf16x8;
typedef __attribute__((ext_vector_type(4))) float f32x4;

__device__ __forceinline__ unsigned short f2bf(float x) {
    unsigned int u = __float_as_uint(x);
    u = (u + 0x7fffu + ((u >> 16) & 1u)) >> 16;   // RNE
    return (unsigned short)u;
}
__device__ __forceinline__ unsigned pk2(float a, float b) {
    return (unsigned)f2bf(a) | ((unsigned)f2bf(b) << 16);
}
__device__ __forceinline__ float rcp_fast(float x) { return __builtin_amdgcn_rcpf(x); }
__device__ __forceinline__ float tanh_fast(float x) {
    float e = __expf(2.0f * x);
    return 1.0f - 2.0f * rcp_fast(e + 1.0f);
}
__device__ __forceinline__ float sigmoid_fast(float x) {
    return rcp_fast(1.0f + __expf(-x));
}

// Swizzle: w1s | w2s | gws (whr/whi/whh B-frag) | wos (wo1/wo2 B-frag) | zero hidden.
__global__ __launch_bounds__(256) void swizzle_weights(
        const float* __restrict__ w1, const float* __restrict__ w2,
        const float* __restrict__ whr, const float* __restrict__ whi,
        const float* __restrict__ whh, const float* __restrict__ wo1,
        const float* __restrict__ wo2,
        unsigned short* __restrict__ w1s, unsigned short* __restrict__ w2s,
        unsigned short* __restrict__ gws, unsigned short* __restrict__ wos,
        unsigned int* __restrict__ zero_region) {
    const int W1N = 3 * 16 * 16 * 64 * 8;   // 393216
    const int W2N = 3 * 16 * 8 * 64 * 8;    // 196608
    const int GWN = 3 * 65536;              // 196608
    const int WON = 2 * 65536;              // 131072
    int idx = blockIdx.x * 256 + threadIdx.x;
    if (idx < W1N) {
        int j = idx & 7, L = (idx >> 3) & 63, kt = (idx >> 9) & 15;
        int nt = (idx >> 13) & 15, i = idx >> 17;
        int n = nt * 16 + (L & 15);
        int k = kt * 32 + ((L >> 4) << 3) + j;
        w1s[idx] = f2bf(w1[((size_t)(i + 1) * H_ + n) * (2 * H_) + k]);
    } else if (idx < W1N + W2N) {
        int t = idx - W1N;
        int j = t & 7, L = (t >> 3) & 63, kt = (t >> 9) & 7;
        int nt = (t >> 12) & 15, i = t >> 16;
        int n = nt * 16 + (L & 15);
        int k = kt * 32 + ((L >> 4) << 3) + j;
        w2s[t] = f2bf(w2[((size_t)(i + 1) * H_ + n) * H_ + k]);
    } else if (idx < W1N + W2N + GWN) {
        int t = idx - (W1N + W2N);
        int j = t & 7, L = (t >> 3) & 63, kt = (t >> 9) & 7;
        int nt = (t >> 12) & 15, mat = t >> 16;
        int n = nt * 16 + (L & 15);
        int k = kt * 32 + ((L >> 4) << 3) + j;
        const float* src = (mat == 0) ? whr : (mat == 1) ? whi : whh;
        gws[t] = f2bf(src[(size_t)n * H_ + k]);
    } else if (idx < W1N + W2N + GWN + WON) {
        int t = idx - (W1N + W2N + GWN);
        int j = t & 7, L = (t >> 3) & 63, kt = (t >> 9) & 7;
        int nt = (t >> 12) & 15, g = t >> 16;
        int n = nt * 16 + (L & 15);
        int k = kt * 32 + ((L >> 4) << 3) + j;
        const float* src = (g == 0) ? wo1 : wo2;
        wos[t] = f2bf(src[(size_t)n * H_ + k]);
    } else {
        int t = idx - (W1N + W2N + GWN + WON);
        if (t < 153600) zero_region[t] = 0u;
    }
}

// U/V per node. U half gets b1 pre-folded.
__global__ __launch_bounds__(256) void uv_kernel(
        const unsigned short* __restrict__ hb, const unsigned short* __restrict__ w1s,
        const float* __restrict__ b1, float* __restrict__ UV) {
    int mm = blockIdx.x / 6;
    int tyh = blockIdx.x % 6;
    int ty = tyh >> 1, half = tyh & 1;
    int lane = threadIdx.x & 63, wid = threadIdx.x >> 6;
    int col = lane & 15, q = lane >> 4;
    const bf16x8* w1f = (const bf16x8*)w1s;

    f32x4 acc[4];
    #pragma unroll
    for (int u = 0; u < 4; ++u) acc[u] = (f32x4){0.f, 0.f, 0.f, 0.f};
    #pragma unroll
    for (int kt = 0; kt < 8; ++kt) {
        bf16x8 a = *(const bf16x8*)&hb[(size_t)(mm * 16 + col) * H_ + kt * 32 + q * 8];
        #pragma unroll
        for (int u = 0; u < 4; ++u) {
            bf16x8 w = w1f[(size_t)((ty * 16 + wid * 4 + u) * 16 + half * 8 + kt) * 64 + lane];
            acc[u] = __builtin_amdgcn_mfma_f32_16x16x32_bf16(a, w, acc[u], 0, 0, 0);
        }
    }
    #pragma unroll
    for (int u = 0; u < 4; ++u) {
        float bias = (half == 0) ? b1[(ty + 1) * H_ + (wid * 4 + u) * 16 + col] : 0.0f;
        #pragma unroll
        for (int r = 0; r < 4; ++r)
            UV[((size_t)(mm * 16 + q * 4 + r) * 3 + ty) * 512 + half * 256 +
               (wid * 4 + u) * 16 + col] = acc[u][r] + bias;
    }
}

// Fused m1-build + GEMM2 + sender-reduction, k-split staging (16 KB LDS).
// Block = (ty, b, recv r). Output scaled by 1/147.
__global__ __launch_bounds__(256, 6) void msgagg_kernel(
        const float* __restrict__ UV, const float* __restrict__ edges,
        const unsigned short* __restrict__ w2s,
        const float* __restrict__ b2, float* __restrict__ aggP, int t) {
    __shared__ unsigned short m1F[16 * 512];   // 16 KB: 4 mt x 4 ktl frags
    __shared__ float relS[64];

    int ty = blockIdx.x / 400;
    int rem = blockIdx.x - ty * 400;
    int b = rem / 50;
    int r = rem - b * 50;
    int tid = threadIdx.x;
    int lane = tid & 63, wid = tid >> 6;
    int col = lane & 15, q = lane >> 4;

    if (tid < 64) {
        float v = 0.0f;
        if (tid < 50 && tid != r) {
            int e = tid * 49 + (r > tid ? r - 1 : r);
            v = edges[(((size_t)b * T_ + t) * E_ + e) * K_ + ty + 1];
        }
        relS[tid] = v;
    }

    int row = wid * 16 + col;                // sender (rows >= 50 give garbage, relS=0)
    int sv = row < N_ ? row : N_ - 1;
    const float* Vrow = &UV[((size_t)(b * N_ + sv) * 3 + ty) * 512 + 256 + q * 8];
    const float* Urow = &UV[((size_t)(b * N_ + r) * 3 + ty) * 512 + q * 8];

    const bf16x8* w2f = (const bf16x8*)w2s;
    f32x4 acc[4][4];
    #pragma unroll
    for (int mt = 0; mt < 4; ++mt)
        #pragma unroll
        for (int u = 0; u < 4; ++u) acc[mt][u] = (f32x4){0.f, 0.f, 0.f, 0.f};

    #pragma unroll
    for (int kh = 0; kh < 2; ++kh) {
        if (kh) __syncthreads();             // prior half's GEMM reads done
        #pragma unroll
        for (int ktl = 0; ktl < 4; ++ktl) {
            int ko = kh * 128 + ktl * 32;
            float4 v0 = *(const float4*)(Vrow + ko);
            float4 v1 = *(const float4*)(Vrow + ko + 4);
            float4 u0 = *(const float4*)(Urow + ko);
            float4 u1 = *(const float4*)(Urow + ko + 4);
            float m0 = tanh_fast(u0.x + v0.x);
            float m1 = tanh_fast(u0.y + v0.y);
            float m2 = tanh_fast(u0.z + v0.z);
            float m3 = tanh_fast(u0.w + v0.w);
            float m4 = tanh_fast(u1.x + v1.x);
            float m5 = tanh_fast(u1.y + v1.y);
            float m6 = tanh_fast(u1.z + v1.z);
            float m7 = tanh_fast(u1.w + v1.w);
            uint4 pk;
            pk.x = pk2(m0, m1); pk.y = pk2(m2, m3);
            pk.z = pk2(m4, m5); pk.w = pk2(m6, m7);
            *(uint4*)&m1F[(wid * 4 + ktl) * 512 + lane * 8] = pk;
        }
        __syncthreads();
        #pragma unroll
        for (int ktl = 0; ktl < 4; ++ktl) {
            bf16x8 a0 = *(const bf16x8*)&m1F[(0 * 4 + ktl) * 512 + lane * 8];
            bf16x8 a1 = *(const bf16x8*)&m1F[(1 * 4 + ktl) * 512 + lane * 8];
            bf16x8 a2 = *(const bf16x8*)&m1F[(2 * 4 + ktl) * 512 + lane * 8];
            bf16x8 a3 = *(const bf16x8*)&m1F[(3 * 4 + ktl) * 512 + lane * 8];
            #pragma unroll
            for (int u = 0; u < 4; ++u) {
                bf16x8 w = w2f[(size_t)((ty * 16 + wid * 4 + u) * 8 + kh * 4 + ktl) * 64
                               + lane];
                acc[0][u] = __builtin_amdgcn_mfma_f32_16x16x32_bf16(a0, w, acc[0][u], 0, 0, 0);
                acc[1][u] = __builtin_amdgcn_mfma_f32_16x16x32_bf16(a1, w, acc[1][u], 0, 0, 0);
                acc[2][u] = __builtin_amdgcn_mfma_f32_16x16x32_bf16(a2, w, acc[2][u], 0, 0, 0);
                acc[3][u] = __builtin_amdgcn_mfma_f32_16x16x32_bf16(a3, w, acc[3][u], 0, 0, 0);
            }
        }
    }
    #pragma unroll
    for (int u = 0; u < 4; ++u) {
        float bias = b2[(ty + 1) * H_ + (wid * 4 + u) * 16 + col];
        float sum = 0.0f;
        #pragma unroll
        for (int mt = 0; mt < 4; ++mt)
            #pragma unroll
            for (int rg = 0; rg < 4; ++rg) {
                int rr = mt * 16 + q * 4 + rg;
                sum += tanh_fast(acc[mt][u][rg] + bias) * relS[rr];
            }
        sum += __shfl_xor(sum, 16);
        sum += __shfl_xor(sum, 32);
        if (lane < 16)
            aggP[(size_t)ty * AP + (size_t)(b * N_ + r) * H_ +
                 (wid * 4 + u) * 16 + col] = sum * (1.0f / 147.0f);
    }
}

// Fused node kernel: gates GEMM (3 mats) + GRU elementwise + o1/o2 MFMA MLP + o3.
__global__ __launch_bounds__(256) void node_kernel(
        const float* __restrict__ inputs, const float* __restrict__ aggP,
        const unsigned short* __restrict__ gws, const unsigned short* __restrict__ wos,
        float* __restrict__ hidden, unsigned short* __restrict__ hidden_bf,
        const float* __restrict__ w_ir, const float* __restrict__ b_ir,
        const float* __restrict__ w_ii, const float* __restrict__ b_ii,
        const float* __restrict__ w_in, const float* __restrict__ b_in,
        const float* __restrict__ b_o1, const float* __restrict__ b_o2,
        const float* __restrict__ w_o3, const float* __restrict__ b_o3,
        float* __restrict__ out, int t) {
    __shared__ unsigned short aggF[8 * 512];
    __shared__ unsigned short hnF[8 * 512];
    __shared__ unsigned short p1F[8 * 512];
    __shared__ float p2L[16 * 260];
    __shared__ float insS[16 * 6];

    int mm = blockIdx.x;
    int tid = threadIdx.x;
    int lane = tid & 63, wid = tid >> 6;
    int col = lane & 15, q = lane >> 4;

    const float* src = (t == 0) ? inputs : out;
    int tt = (t == 0) ? 0 : (t - 1);

    #pragma unroll
    for (int s = 0; s < 2; ++s) {
        int slot = tid + s * 256;
        int kt = slot >> 6, L = slot & 63;
        int row = mm * 16 + (L & 15);
        int k0 = kt * 32 + ((L >> 4) << 3);
        const float* p = &aggP[(size_t)row * H_ + k0];
        float4 a0 = *(const float4*)(p);
        float4 a1 = *(const float4*)(p + 4);
        float4 b0 = *(const float4*)(p + AP);
        float4 b1 = *(const float4*)(p + AP + 4);
        float4 c0 = *(const float4*)(p + 2 * AP);
        float4 c1 = *(const float4*)(p + 2 * AP + 4);
        uint4 pk;
        pk.x = pk2(a0.x + b0.x + c0.x, a0.y + b0.y + c0.y);
        pk.y = pk2(a0.z + b0.z + c0.z, a0.w + b0.w + c0.w);
        pk.z = pk2(a1.x + b1.x + c1.x, a1.y + b1.y + c1.y);
        pk.w = pk2(a1.z + b1.z + c1.z, a1.w + b1.w + c1.w);
        *(uint4*)&aggF[(size_t)kt * 512 + L * 8] = pk;
    }
    if (tid < 96) {
        int rl = tid / 6, c = tid - rl * 6;
        int row = mm * 16 + rl;
        int b = row / 50, n = row - b * 50;
        insS[rl * 6 + c] = src[(((size_t)b * T_ + tt) * N_ + n) * IN_ + c];
    }
    __syncthreads();

    const bf16x8* gwf = (const bf16x8*)gws;
    f32x4 acc[3][4];
    #pragma unroll
    for (int m = 0; m < 3; ++m)
        #pragma unroll
        for (int u = 0; u < 4; ++u) acc[m][u] = (f32x4){0.f, 0.f, 0.f, 0.f};
    #pragma unroll
    for (int kt = 0; kt < 8; ++kt) {
        bf16x8 a = *(const bf16x8*)&aggF[kt * 512 + lane * 8];
        #pragma unroll
        for (int m = 0; m < 3; ++m)
            #pragma unroll
            for (int u = 0; u < 4; ++u) {
                bf16x8 w = gwf[(size_t)((m * 16 + wid * 4 + u) * 8 + kt) * 64 + lane];
                acc[m][u] = __builtin_amdgcn_mfma_f32_16x16x32_bf16(a, w, acc[m][u], 0, 0, 0);
            }
    }

    #pragma unroll
    for (int u = 0; u < 4; ++u) {
        int h = (wid * 4 + u) * 16 + col;
        float bir = b_ir[h], bii = b_ii[h], bin_ = b_in[h];
        float wir[6], wii[6], win[6];
        #pragma unroll
        for (int c = 0; c < 6; ++c) {
            wir[c] = w_ir[h * 6 + c];
            wii[c] = w_ii[h * 6 + c];
            win[c] = w_in[h * 6 + c];
        }
        #pragma unroll
        for (int rg = 0; rg < 4; ++rg) {
            int rl = q * 4 + rg;
            int row = mm * 16 + rl;
            float xr = bir, xi = bii, xn = bin_;
            #pragma unroll
            for (int c = 0; c < 6; ++c) {
                float iv = insS[rl * 6 + c];
                xr += wir[c] * iv;
                xi += wii[c] * iv;
                xn += win[c] * iv;
            }
            float rgate = sigmoid_fast(xr + acc[0][u][rg]);
            float igate = sigmoid_fast(xi + acc[1][u][rg]);
            float nn = tanh_fast(xn + rgate * acc[2][u][rg]);
            size_t off = (size_t)row * H_ + h;
            float hold = hidden[off];
            float hnew = (1.0f - igate) * nn + igate * hold;
            hidden[off] = hnew;
            hidden_bf[off] = f2bf(hnew);
            hnF[(h >> 5) * 512 + (((h >> 3) & 3) * 16 + rl) * 8 + (h & 7)] = f2bf(hnew);
        }
    }
    __syncthreads();

    const bf16x8* wof = (const bf16x8*)wos;
    f32x4 a1v[4];
    #pragma unroll
    for (int u = 0; u < 4; ++u) a1v[u] = (f32x4){0.f, 0.f, 0.f, 0.f};
    #pragma unroll
    for (int kt = 0; kt < 8; ++kt) {
        bf16x8 a = *(const bf16x8*)&hnF[kt * 512 + lane * 8];
        #pragma unroll
        for (int u = 0; u < 4; ++u) {
            bf16x8 w = wof[(size_t)((wid * 4 + u) * 8 + kt) * 64 + lane];
            a1v[u] = __builtin_amdgcn_mfma_f32_16x16x32_bf16(a, w, a1v[u], 0, 0, 0);
        }
    }
    #pragma unroll
    for (int u = 0; u < 4; ++u) {
        int h = (wid * 4 + u) * 16 + col;
        float bo = b_o1[h];
        #pragma unroll
        for (int rg = 0; rg < 4; ++rg) {
            int rl = q * 4 + rg;
            float v = fmaxf(a1v[u][rg] + bo, 0.0f);
            p1F[(h >> 5) * 512 + (((h >> 3) & 3) * 16 + rl) * 8 + (h & 7)] = f2bf(v);
        }
    }
    __syncthreads();

    f32x4 a2v[4];
    #pragma unroll
    for (int u = 0; u < 4; ++u) a2v[u] = (f32x4){0.f, 0.f, 0.f, 0.f};
    #pragma unroll
    for (int kt = 0; kt < 8; ++kt) {
        bf16x8 a = *(const bf16x8*)&p1F[kt * 512 + lane * 8];
        #pragma unroll
        for (int u = 0; u < 4; ++u) {
            bf16x8 w = wof[(size_t)((16 + wid * 4 + u) * 8 + kt) * 64 + lane];
            a2v[u] = __builtin_amdgcn_mfma_f32_16x16x32_bf16(a, w, a2v[u], 0, 0, 0);
        }
    }
    #pragma unroll
    for (int u = 0; u < 4; ++u) {
        int h = (wid * 4 + u) * 16 + col;
        float bo = b_o2[h];
        #pragma unroll
        for (int rg = 0; rg < 4; ++rg) {
            int rl = q * 4 + rg;
            p2L[rl * 260 + h] = fmaxf(a2v[u][rg] + bo, 0.0f);
        }
    }
    __syncthreads();

    if (tid < 96) {
        int rl = tid / 6, c = tid - rl * 6;
        int row = mm * 16 + rl;
        float acc3 = b_o3[c];
        for (int k = 0; k < 256; k += 4) {
            float4 w = *(const float4*)&w_o3[c * 256 + k];
            float4 p = *(const float4*)&p2L[rl * 260 + k];
            acc3 += w.x * p.x + w.y * p.y + w.z * p.z + w.w * p.w;
        }
        int b = row / 50, n = row - b * 50;
        out[(((size_t)b * T_ + t) * N_ + n) * IN_ + c] = insS[rl * 6 + c] + acc3;
    }
}

extern "C" void kernel_launch(void* const* d_in, const int* in_sizes, int n_in,
                              void* d_out, int out_size, void* d_ws, size_t ws_size,
                              hipStream_t stream) {
    const float* inputs = (const float*)d_in[0];
    const float* edges  = (const float*)d_in[1];
    const float* msg_w1 = (const float*)d_in[2];
    const float* msg_b1 = (const float*)d_in[3];
    const float* msg_w2 = (const float*)d_in[4];
    const float* msg_b2 = (const float*)d_in[5];
    const float* w_hr = (const float*)d_in[6];
    const float* w_hi = (const float*)d_in[7];
    const float* w_hh = (const float*)d_in[8];
    const float* w_ir = (const float*)d_in[9];
    const float* b_ir = (const float*)d_in[10];
    const float* w_ii = (const float*)d_in[11];
    const float* b_ii = (const float*)d_in[12];
    const float* w_in = (const float*)d_in[13];
    const float* b_in = (const float*)d_in[14];
    const float* w_o1 = (const float*)d_in[15];
    const float* b_o1 = (const float*)d_in[16];
    const float* w_o2 = (const float*)d_in[17];
    const float* b_o2 = (const float*)d_in[18];
    const float* w_o3 = (const float*)d_in[19];
    const float* b_o3 = (const float*)d_in[20];
    float* out = (float*)d_out;
    char* ws = (char*)d_ws;

    float* hidden            = (float*)(ws);                       // 409,600 B
    unsigned short* hidden_bf= (unsigned short*)(ws + 409600);     // 204,800 B
    float* UV                = (float*)(ws + 614400);              // 2,457,600 B
    float* aggP              = (float*)(ws + 3072000);             // 1,228,800 B
    unsigned short* w1s      = (unsigned short*)(ws + 4300800);    // 786,432 B
    unsigned short* w2s      = (unsigned short*)(ws + 5087232);    // 393,216 B
    unsigned short* gws      = (unsigned short*)(ws + 5480448);    // 393,216 B
    unsigned short* wos      = (unsigned short*)(ws + 5873664);    // 262,144 B

    swizzle_weights<<<dim3(4184), dim3(256), 0, stream>>>(
        msg_w1, msg_w2, w_hr, w_hi, w_hh, w_o1, w_o2, w1s, w2s, gws, wos,
        (unsigned int*)ws);

    for (int t = 0; t < T_; ++t) {
        uv_kernel<<<dim3(150), dim3(256), 0, stream>>>(hidden_bf, w1s, msg_b1, UV);
        msgagg_kernel<<<dim3(1200), dim3(256), 0, stream>>>(
            UV, edges, w2s, msg_b2, aggP, t);
        node_kernel<<<dim3(25), dim3(256), 0, stream>>>(
            inputs, aggP, gws, wos, hidden, hidden_bf,
            w_ir, b_ir, w_ii, b_ii, w_in, b_in, b_o1, b_o2, w_o3, b_o3, out, t);
    }
}

// Round 11
// 629.264 us; speedup vs baseline: 2.0062x; 2.0062x over previous
//
#include <hip/hip_runtime.h>
#include <hip/hip_bf16.h>
#include <stdint.h>

#define B_ 8
#define T_ 10
#define N_ 50
#define IN_ 6
#define H_ 256
#define K_ 4
#define E_ 2450
#define ROWS 400           // B_*N_
#define AP 102400          // ROWS*H_

typedef __attribute__((ext_vector_type(8))) __bf16 bf16x8;
typedef __attribute__((ext_vector_type(4))) float f32x4;

__device__ __forceinline__ unsigned short f2bf(float x) {
    unsigned int u = __float_as_uint(x);
    u = (u + 0x7fffu + ((u >> 16) & 1u)) >> 16;   // RNE
    return (unsigned short)u;
}
__device__ __forceinline__ unsigned pk2(float a, float b) {
    return (unsigned)f2bf(a) | ((unsigned)f2bf(b) << 16);
}
__device__ __forceinline__ float rcp_fast(float x) { return __builtin_amdgcn_rcpf(x); }
__device__ __forceinline__ float tanh_fast(float x) {
    float e = __expf(2.0f * x);
    return 1.0f - 2.0f * rcp_fast(e + 1.0f);
}
__device__ __forceinline__ float sigmoid_fast(float x) {
    return rcp_fast(1.0f + __expf(-x));
}

// Swizzle: w1s | w2s | gws (whr/whi/whh B-frag) | wos (wo1/wo2 B-frag) | zero hidden.
__global__ __launch_bounds__(256) void swizzle_weights(
        const float* __restrict__ w1, const float* __restrict__ w2,
        const float* __restrict__ whr, const float* __restrict__ whi,
        const float* __restrict__ whh, const float* __restrict__ wo1,
        const float* __restrict__ wo2,
        unsigned short* __restrict__ w1s, unsigned short* __restrict__ w2s,
        unsigned short* __restrict__ gws, unsigned short* __restrict__ wos,
        unsigned int* __restrict__ zero_region) {
    const int W1N = 3 * 16 * 16 * 64 * 8;   // 393216
    const int W2N = 3 * 16 * 8 * 64 * 8;    // 196608
    const int GWN = 3 * 65536;              // 196608
    const int WON = 2 * 65536;              // 131072
    int idx = blockIdx.x * 256 + threadIdx.x;
    if (idx < W1N) {
        int j = idx & 7, L = (idx >> 3) & 63, kt = (idx >> 9) & 15;
        int nt = (idx >> 13) & 15, i = idx >> 17;
        int n = nt * 16 + (L & 15);
        int k = kt * 32 + ((L >> 4) << 3) + j;
        w1s[idx] = f2bf(w1[((size_t)(i + 1) * H_ + n) * (2 * H_) + k]);
    } else if (idx < W1N + W2N) {
        int t = idx - W1N;
        int j = t & 7, L = (t >> 3) & 63, kt = (t >> 9) & 7;
        int nt = (t >> 12) & 15, i = t >> 16;
        int n = nt * 16 + (L & 15);
        int k = kt * 32 + ((L >> 4) << 3) + j;
        w2s[t] = f2bf(w2[((size_t)(i + 1) * H_ + n) * H_ + k]);
    } else if (idx < W1N + W2N + GWN) {
        int t = idx - (W1N + W2N);
        int j = t & 7, L = (t >> 3) & 63, kt = (t >> 9) & 7;
        int nt = (t >> 12) & 15, mat = t >> 16;
        int n = nt * 16 + (L & 15);
        int k = kt * 32 + ((L >> 4) << 3) + j;
        const float* src = (mat == 0) ? whr : (mat == 1) ? whi : whh;
        gws[t] = f2bf(src[(size_t)n * H_ + k]);
    } else if (idx < W1N + W2N + GWN + WON) {
        int t = idx - (W1N + W2N + GWN);
        int j = t & 7, L = (t >> 3) & 63, kt = (t >> 9) & 7;
        int nt = (t >> 12) & 15, g = t >> 16;
        int n = nt * 16 + (L & 15);
        int k = kt * 32 + ((L >> 4) << 3) + j;
        const float* src = (g == 0) ? wo1 : wo2;
        wos[t] = f2bf(src[(size_t)n * H_ + k]);
    } else {
        int t = idx - (W1N + W2N + GWN + WON);
        if (t < 153600) zero_region[t] = 0u;
    }
}

// U/V per node. U half gets b1 pre-folded.
__global__ __launch_bounds__(256) void uv_kernel(
        const unsigned short* __restrict__ hb, const unsigned short* __restrict__ w1s,
        const float* __restrict__ b1, float* __restrict__ UV) {
    int mm = blockIdx.x / 6;
    int tyh = blockIdx.x % 6;
    int ty = tyh >> 1, half = tyh & 1;
    int lane = threadIdx.x & 63, wid = threadIdx.x >> 6;
    int col = lane & 15, q = lane >> 4;
    const bf16x8* w1f = (const bf16x8*)w1s;

    f32x4 acc[4];
    #pragma unroll
    for (int u = 0; u < 4; ++u) acc[u] = (f32x4){0.f, 0.f, 0.f, 0.f};
    #pragma unroll
    for (int kt = 0; kt < 8; ++kt) {
        bf16x8 a = *(const bf16x8*)&hb[(size_t)(mm * 16 + col) * H_ + kt * 32 + q * 8];
        #pragma unroll
        for (int u = 0; u < 4; ++u) {
            bf16x8 w = w1f[(size_t)((ty * 16 + wid * 4 + u) * 16 + half * 8 + kt) * 64 + lane];
            acc[u] = __builtin_amdgcn_mfma_f32_16x16x32_bf16(a, w, acc[u], 0, 0, 0);
        }
    }
    #pragma unroll
    for (int u = 0; u < 4; ++u) {
        float bias = (half == 0) ? b1[(ty + 1) * H_ + (wid * 4 + u) * 16 + col] : 0.0f;
        #pragma unroll
        for (int r = 0; r < 4; ++r)
            UV[((size_t)(mm * 16 + q * 4 + r) * 3 + ty) * 512 + half * 256 +
               (wid * 4 + u) * 16 + col] = acc[u][r] + bias;
    }
}

// Fused m1-build + GEMM2 + sender-reduction, k-split staging (16 KB LDS).
// Block = (ty, b, recv r). Output scaled by 1/147.
__global__ __launch_bounds__(256, 4) void msgagg_kernel(
        const float* __restrict__ UV, const float* __restrict__ edges,
        const unsigned short* __restrict__ w2s,
        const float* __restrict__ b2, float* __restrict__ aggP, int t) {
    __shared__ unsigned short m1F[16 * 512];   // 16 KB: 4 mt x 4 ktl frags
    __shared__ float relS[64];

    int ty = blockIdx.x / 400;
    int rem = blockIdx.x - ty * 400;
    int b = rem / 50;
    int r = rem - b * 50;
    int tid = threadIdx.x;
    int lane = tid & 63, wid = tid >> 6;
    int col = lane & 15, q = lane >> 4;

    if (tid < 64) {
        float v = 0.0f;
        if (tid < 50 && tid != r) {
            int e = tid * 49 + (r > tid ? r - 1 : r);
            v = edges[(((size_t)b * T_ + t) * E_ + e) * K_ + ty + 1];
        }
        relS[tid] = v;
    }

    int row = wid * 16 + col;                // sender (rows >= 50 give garbage, relS=0)
    int sv = row < N_ ? row : N_ - 1;
    const float* Vrow = &UV[((size_t)(b * N_ + sv) * 3 + ty) * 512 + 256 + q * 8];
    const float* Urow = &UV[((size_t)(b * N_ + r) * 3 + ty) * 512 + q * 8];

    const bf16x8* w2f = (const bf16x8*)w2s;
    f32x4 acc[4][4];
    #pragma unroll
    for (int mt = 0; mt < 4; ++mt)
        #pragma unroll
        for (int u = 0; u < 4; ++u) acc[mt][u] = (f32x4){0.f, 0.f, 0.f, 0.f};

    #pragma unroll
    for (int kh = 0; kh < 2; ++kh) {
        if (kh) __syncthreads();             // prior half's GEMM reads done
        #pragma unroll
        for (int ktl = 0; ktl < 4; ++ktl) {
            int ko = kh * 128 + ktl * 32;
            float4 v0 = *(const float4*)(Vrow + ko);
            float4 v1 = *(const float4*)(Vrow + ko + 4);
            float4 u0 = *(const float4*)(Urow + ko);
            float4 u1 = *(const float4*)(Urow + ko + 4);
            float m0 = tanh_fast(u0.x + v0.x);
            float m1 = tanh_fast(u0.y + v0.y);
            float m2 = tanh_fast(u0.z + v0.z);
            float m3 = tanh_fast(u0.w + v0.w);
            float m4 = tanh_fast(u1.x + v1.x);
            float m5 = tanh_fast(u1.y + v1.y);
            float m6 = tanh_fast(u1.z + v1.z);
            float m7 = tanh_fast(u1.w + v1.w);
            uint4 pk;
            pk.x = pk2(m0, m1); pk.y = pk2(m2, m3);
            pk.z = pk2(m4, m5); pk.w = pk2(m6, m7);
            *(uint4*)&m1F[(wid * 4 + ktl) * 512 + lane * 8] = pk;
        }
        __syncthreads();
        #pragma unroll
        for (int ktl = 0; ktl < 4; ++ktl) {
            bf16x8 a0 = *(const bf16x8*)&m1F[(0 * 4 + ktl) * 512 + lane * 8];
            bf16x8 a1 = *(const bf16x8*)&m1F[(1 * 4 + ktl) * 512 + lane * 8];
            bf16x8 a2 = *(const bf16x8*)&m1F[(2 * 4 + ktl) * 512 + lane * 8];
            bf16x8 a3 = *(const bf16x8*)&m1F[(3 * 4 + ktl) * 512 + lane * 8];
            #pragma unroll
            for (int u = 0; u < 4; ++u) {
                bf16x8 w = w2f[(size_t)((ty * 16 + wid * 4 + u) * 8 + kh * 4 + ktl) * 64
                               + lane];
                acc[0][u] = __builtin_amdgcn_mfma_f32_16x16x32_bf16(a0, w, acc[0][u], 0, 0, 0);
                acc[1][u] = __builtin_amdgcn_mfma_f32_16x16x32_bf16(a1, w, acc[1][u], 0, 0, 0);
                acc[2][u] = __builtin_amdgcn_mfma_f32_16x16x32_bf16(a2, w, acc[2][u], 0, 0, 0);
                acc[3][u] = __builtin_amdgcn_mfma_f32_16x16x32_bf16(a3, w, acc[3][u], 0, 0, 0);
            }
        }
    }
    #pragma unroll
    for (int u = 0; u < 4; ++u) {
        float bias = b2[(ty + 1) * H_ + (wid * 4 + u) * 16 + col];
        float sum = 0.0f;
        #pragma unroll
        for (int mt = 0; mt < 4; ++mt)
            #pragma unroll
            for (int rg = 0; rg < 4; ++rg) {
                int rr = mt * 16 + q * 4 + rg;
                sum += tanh_fast(acc[mt][u][rg] + bias) * relS[rr];
            }
        sum += __shfl_xor(sum, 16);
        sum += __shfl_xor(sum, 32);
        if (lane < 16)
            aggP[(size_t)ty * AP + (size_t)(b * N_ + r) * H_ +
                 (wid * 4 + u) * 16 + col] = sum * (1.0f / 147.0f);
    }
}

// Fused node kernel: gates GEMM (3 mats) + GRU elementwise + o1/o2 MFMA MLP + o3.
__global__ __launch_bounds__(256) void node_kernel(
        const float* __restrict__ inputs, const float* __restrict__ aggP,
        const unsigned short* __restrict__ gws, const unsigned short* __restrict__ wos,
        float* __restrict__ hidden, unsigned short* __restrict__ hidden_bf,
        const float* __restrict__ w_ir, const float* __restrict__ b_ir,
        const float* __restrict__ w_ii, const float* __restrict__ b_ii,
        const float* __restrict__ w_in, const float* __restrict__ b_in,
        const float* __restrict__ b_o1, const float* __restrict__ b_o2,
        const float* __restrict__ w_o3, const float* __restrict__ b_o3,
        float* __restrict__ out, int t) {
    __shared__ unsigned short aggF[8 * 512];
    __shared__ unsigned short hnF[8 * 512];
    __shared__ unsigned short p1F[8 * 512];
    __shared__ float p2L[16 * 260];
    __shared__ float insS[16 * 6];

    int mm = blockIdx.x;
    int tid = threadIdx.x;
    int lane = tid & 63, wid = tid >> 6;
    int col = lane & 15, q = lane >> 4;

    const float* src = (t == 0) ? inputs : out;
    int tt = (t == 0) ? 0 : (t - 1);

    #pragma unroll
    for (int s = 0; s < 2; ++s) {
        int slot = tid + s * 256;
        int kt = slot >> 6, L = slot & 63;
        int row = mm * 16 + (L & 15);
        int k0 = kt * 32 + ((L >> 4) << 3);
        const float* p = &aggP[(size_t)row * H_ + k0];
        float4 a0 = *(const float4*)(p);
        float4 a1 = *(const float4*)(p + 4);
        float4 b0 = *(const float4*)(p + AP);
        float4 b1 = *(const float4*)(p + AP + 4);
        float4 c0 = *(const float4*)(p + 2 * AP);
        float4 c1 = *(const float4*)(p + 2 * AP + 4);
        uint4 pk;
        pk.x = pk2(a0.x + b0.x + c0.x, a0.y + b0.y + c0.y);
        pk.y = pk2(a0.z + b0.z + c0.z, a0.w + b0.w + c0.w);
        pk.z = pk2(a1.x + b1.x + c1.x, a1.y + b1.y + c1.y);
        pk.w = pk2(a1.z + b1.z + c1.z, a1.w + b1.w + c1.w);
        *(uint4*)&aggF[(size_t)kt * 512 + L * 8] = pk;
    }
    if (tid < 96) {
        int rl = tid / 6, c = tid - rl * 6;
        int row = mm * 16 + rl;
        int b = row / 50, n = row - b * 50;
        insS[rl * 6 + c] = src[(((size_t)b * T_ + tt) * N_ + n) * IN_ + c];
    }
    __syncthreads();

    const bf16x8* gwf = (const bf16x8*)gws;
    f32x4 acc[3][4];
    #pragma unroll
    for (int m = 0; m < 3; ++m)
        #pragma unroll
        for (int u = 0; u < 4; ++u) acc[m][u] = (f32x4){0.f, 0.f, 0.f, 0.f};
    #pragma unroll
    for (int kt = 0; kt < 8; ++kt) {
        bf16x8 a = *(const bf16x8*)&aggF[kt * 512 + lane * 8];
        #pragma unroll
        for (int m = 0; m < 3; ++m)
            #pragma unroll
            for (int u = 0; u < 4; ++u) {
                bf16x8 w = gwf[(size_t)((m * 16 + wid * 4 + u) * 8 + kt) * 64 + lane];
                acc[m][u] = __builtin_amdgcn_mfma_f32_16x16x32_bf16(a, w, acc[m][u], 0, 0, 0);
            }
    }

    #pragma unroll
    for (int u = 0; u < 4; ++u) {
        int h = (wid * 4 + u) * 16 + col;
        float bir = b_ir[h], bii = b_ii[h], bin_ = b_in[h];
        float wir[6], wii[6], win[6];
        #pragma unroll
        for (int c = 0; c < 6; ++c) {
            wir[c] = w_ir[h * 6 + c];
            wii[c] = w_ii[h * 6 + c];
            win[c] = w_in[h * 6 + c];
        }
        #pragma unroll
        for (int rg = 0; rg < 4; ++rg) {
            int rl = q * 4 + rg;
            int row = mm * 16 + rl;
            float xr = bir, xi = bii, xn = bin_;
            #pragma unroll
            for (int c = 0; c < 6; ++c) {
                float iv = insS[rl * 6 + c];
                xr += wir[c] * iv;
                xi += wii[c] * iv;
                xn += win[c] * iv;
            }
            float rgate = sigmoid_fast(xr + acc[0][u][rg]);
            float igate = sigmoid_fast(xi + acc[1][u][rg]);
            float nn = tanh_fast(xn + rgate * acc[2][u][rg]);
            size_t off = (size_t)row * H_ + h;
            float hold = hidden[off];
            float hnew = (1.0f - igate) * nn + igate * hold;
            hidden[off] = hnew;
            hidden_bf[off] = f2bf(hnew);
            hnF[(h >> 5) * 512 + (((h >> 3) & 3) * 16 + rl) * 8 + (h & 7)] = f2bf(hnew);
        }
    }
    __syncthreads();

    const bf16x8* wof = (const bf16x8*)wos;
    f32x4 a1v[4];
    #pragma unroll
    for (int u = 0; u < 4; ++u) a1v[u] = (f32x4){0.f, 0.f, 0.f, 0.f};
    #pragma unroll
    for (int kt = 0; kt < 8; ++kt) {
        bf16x8 a = *(const bf16x8*)&hnF[kt * 512 + lane * 8];
        #pragma unroll
        for (int u = 0; u < 4; ++u) {
            bf16x8 w = wof[(size_t)((wid * 4 + u) * 8 + kt) * 64 + lane];
            a1v[u] = __builtin_amdgcn_mfma_f32_16x16x32_bf16(a, w, a1v[u], 0, 0, 0);
        }
    }
    #pragma unroll
    for (int u = 0; u < 4; ++u) {
        int h = (wid * 4 + u) * 16 + col;
        float bo = b_o1[h];
        #pragma unroll
        for (int rg = 0; rg < 4; ++rg) {
            int rl = q * 4 + rg;
            float v = fmaxf(a1v[u][rg] + bo, 0.0f);
            p1F[(h >> 5) * 512 + (((h >> 3) & 3) * 16 + rl) * 8 + (h & 7)] = f2bf(v);
        }
    }
    __syncthreads();

    f32x4 a2v[4];
    #pragma unroll
    for (int u = 0; u < 4; ++u) a2v[u] = (f32x4){0.f, 0.f, 0.f, 0.f};
    #pragma unroll
    for (int kt = 0; kt < 8; ++kt) {
        bf16x8 a = *(const bf16x8*)&p1F[kt * 512 + lane * 8];
        #pragma unroll
        for (int u = 0; u < 4; ++u) {
            bf16x8 w = wof[(size_t)((16 + wid * 4 + u) * 8 + kt) * 64 + lane];
            a2v[u] = __builtin_amdgcn_mfma_f32_16x16x32_bf16(a, w, a2v[u], 0, 0, 0);
        }
    }
    #pragma unroll
    for (int u = 0; u < 4; ++u) {
        int h = (wid * 4 + u) * 16 + col;
        float bo = b_o2[h];
        #pragma unroll
        for (int rg = 0; rg < 4; ++rg) {
            int rl = q * 4 + rg;
            p2L[rl * 260 + h] = fmaxf(a2v[u][rg] + bo, 0.0f);
        }
    }
    __syncthreads();

    if (tid < 96) {
        int rl = tid / 6, c = tid - rl * 6;
        int row = mm * 16 + rl;
        float acc3 = b_o3[c];
        for (int k = 0; k < 256; k += 4) {
            float4 w = *(const float4*)&w_o3[c * 256 + k];
            float4 p = *(const float4*)&p2L[rl * 260 + k];
            acc3 += w.x * p.x + w.y * p.y + w.z * p.z + w.w * p.w;
        }
        int b = row / 50, n = row - b * 50;
        out[(((size_t)b * T_ + t) * N_ + n) * IN_ + c] = insS[rl * 6 + c] + acc3;
    }
}

extern "C" void kernel_launch(void* const* d_in, const int* in_sizes, int n_in,
                              void* d_out, int out_size, void* d_ws, size_t ws_size,
                              hipStream_t stream) {
    const float* inputs = (const float*)d_in[0];
    const float* edges  = (const float*)d_in[1];
    const float* msg_w1 = (const float*)d_in[2];
    const float* msg_b1 = (const float*)d_in[3];
    const float* msg_w2 = (const float*)d_in[4];
    const float* msg_b2 = (const float*)d_in[5];
    const float* w_hr = (const float*)d_in[6];
    const float* w_hi = (const float*)d_in[7];
    const float* w_hh = (const float*)d_in[8];
    const float* w_ir = (const float*)d_in[9];
    const float* b_ir = (const float*)d_in[10];
    const float* w_ii = (const float*)d_in[11];
    const float* b_ii = (const float*)d_in[12];
    const float* w_in = (const float*)d_in[13];
    const float* b_in = (const float*)d_in[14];
    const float* w_o1 = (const float*)d_in[15];
    const float* b_o1 = (const float*)d_in[16];
    const float* w_o2 = (const float*)d_in[17];
    const float* b_o2 = (const float*)d_in[18];
    const float* w_o3 = (const float*)d_in[19];
    const float* b_o3 = (const float*)d_in[20];
    float* out = (float*)d_out;
    char* ws = (char*)d_ws;

    float* hidden            = (float*)(ws);                       // 409,600 B
    unsigned short* hidden_bf= (unsigned short*)(ws + 409600);     // 204,800 B
    float* UV                = (float*)(ws + 614400);              // 2,457,600 B
    float* aggP              = (float*)(ws + 3072000);             // 1,228,800 B
    unsigned short* w1s      = (unsigned short*)(ws + 4300800);    // 786,432 B
    unsigned short* w2s      = (unsigned short*)(ws + 5087232);    // 393,216 B
    unsigned short* gws      = (unsigned short*)(ws + 5480448);    // 393,216 B
    unsigned short* wos      = (unsigned short*)(ws + 5873664);    // 262,144 B

    swizzle_weights<<<dim3(4184), dim3(256), 0, stream>>>(
        msg_w1, msg_w2, w_hr, w_hi, w_hh, w_o1, w_o2, w1s, w2s, gws, wos,
        (unsigned int*)ws);

    for (int t = 0; t < T_; ++t) {
        uv_kernel<<<dim3(150), dim3(256), 0, stream>>>(hidden_bf, w1s, msg_b1, UV);
        msgagg_kernel<<<dim3(1200), dim3(256), 0, stream>>>(
            UV, edges, w2s, msg_b2, aggP, t);
        node_kernel<<<dim3(25), dim3(256), 0, stream>>>(
            inputs, aggP, gws, wos, hidden, hidden_bf,
            w_ir, b_ir, w_ii, b_ii, w_in, b_in, b_o1, b_o2, w_o3, b_o3, out, t);
    }
}